// Round 12
// baseline (380.227 us; speedup 1.0000x reference)
//
#include <hip/hip_runtime.h>
#include <math.h>
#include <float.h>
#include <limits.h>

#define BN      32768   // B*N query rows
#define D_IN    1024
#define E_DIM   128
#define CB_N    8192

typedef _Float16 f16x8 __attribute__((ext_vector_type(8)));
typedef _Float16 f16x4 __attribute__((ext_vector_type(4)));
typedef float    f32x4 __attribute__((ext_vector_type(4)));

// Workspace:
//   ph  : [CB_N/16][4][64][8] f16   2 MB  (ncb*256 hi, B-frag packed)
//   pl  : same                      2 MB
//   rph : [32*8][64][8] f16         0.25 MB (rp*64 hi, B-frag packed)
//   rpl : same                      0.25 MB

// ---------------------------------------------------------------------------
// Kernel 1 (fused packs): blocks [0,512) pack codebook, blocks [512,544)
// pack rp via LDS-staged coalesced loads. (validated r1-r11)
// ---------------------------------------------------------------------------
__global__ __launch_bounds__(256) void pack_all_kernel(
    const float* __restrict__ cb, _Float16* __restrict__ ph,
    _Float16* __restrict__ pl,
    const float* __restrict__ rp, _Float16* __restrict__ rph,
    _Float16* __restrict__ rpl) {
    __shared__ float L[16][129];
    __shared__ float R[32][132];
    const int t = threadIdx.x;
    const int b = blockIdx.x;

    if (b < 512) {
        const int g = b;
        const int c = t >> 4, p = t & 15;
        const float4 v0 = *(const float4*)&cb[(size_t)(g * 16 + c) * E_DIM + p * 8];
        const float4 v1 = *(const float4*)&cb[(size_t)(g * 16 + c) * E_DIM + p * 8 + 4];
        float ss = v0.x * v0.x + v0.y * v0.y + v0.z * v0.z + v0.w * v0.w
                 + v1.x * v1.x + v1.y * v1.y + v1.z * v1.z + v1.w * v1.w;
#pragma unroll
        for (int m = 1; m < 16; m <<= 1) ss += __shfl_xor(ss, m);
        const float inv = 256.0f / fmaxf(sqrtf(ss), 1e-12f);

        L[c][p * 8 + 0] = v0.x * inv; L[c][p * 8 + 1] = v0.y * inv;
        L[c][p * 8 + 2] = v0.z * inv; L[c][p * 8 + 3] = v0.w * inv;
        L[c][p * 8 + 4] = v1.x * inv; L[c][p * 8 + 5] = v1.y * inv;
        L[c][p * 8 + 6] = v1.z * inv; L[c][p * 8 + 7] = v1.w * inv;
        __syncthreads();

        const int kb = t >> 6, lane = t & 63;
        const int quad = (lane >> 4), col = lane & 15;
        f16x8 h, l;
#pragma unroll
        for (int j = 0; j < 8; ++j) {
            const float v = L[col][kb * 32 + quad * 8 + j];
            const _Float16 hv = (_Float16)v;
            h[j] = hv;
            l[j] = (_Float16)(v - (float)hv);
        }
        const size_t off = ((size_t)(g * 4 + kb) * 64 + lane) * 8;
        *(f16x8*)&ph[off] = h;
        *(f16x8*)&pl[off] = l;
    } else {
        const int kb = b - 512;
        const int r = t >> 3, c0 = (t & 7) * 16;
#pragma unroll
        for (int i = 0; i < 4; ++i)
            *(float4*)&R[r][c0 + i * 4] =
                *(const float4*)&rp[(size_t)(kb * 32 + r) * E_DIM + c0 + i * 4];
        __syncthreads();

        const int w = t >> 6, lane = t & 63;
        const int quad = lane >> 4, col = lane & 15;
#pragma unroll
        for (int h2 = 0; h2 < 2; ++h2) {
            const int nt = w * 2 + h2;
            f16x8 hh, ll;
#pragma unroll
            for (int j = 0; j < 8; ++j) {
                const float v = R[quad * 8 + j][nt * 16 + col] * 64.0f;
                const _Float16 hv = (_Float16)v;
                hh[j] = hv;
                ll[j] = (_Float16)(v - (float)hv);
            }
            const size_t off = ((size_t)((kb * 8 + nt) * 64) + lane) * 8;
            *(f16x8*)&rph[off] = hh;
            *(f16x8*)&rpl[off] = ll;
        }
    }
}

// ---------------------------------------------------------------------------
// Kernel 2 (r12): r11 (B-reuse x4, single-buffer pipelined B) with ONE
// change: A-frags pre-packed into LDS as f16 hi/lo ONCE (wave w extracts
// m-tile w, publishes; packed region aliases the dead f32 P buffer).
// Phase-2 A-access is then a bare ds_read_b128 -- the compiler's per-tile
// remat (forced by the ~240-reg live set at VGPR_Count=112) no longer
// redoes the f32->f16 hi/lo cvt chain (was ~1000+ VALU cy/tile/SIMD =
// the anomalous VALUBusy 32% and the session-long ~40% MfmaUtil cap).
// Values, MFMA order, argmax, merge: bit-identical to r11 -> absmax 0.
// ---------------------------------------------------------------------------
#define PPITCH  132   // phase-2 proj buffer row pitch (dwords), 528 B 16B-aligned

__global__ __launch_bounds__(256, 2) void fused_kernel(
    const float* __restrict__ x,
    const _Float16* __restrict__ rph, const _Float16* __restrict__ rpl,
    const _Float16* __restrict__ ph, const _Float16* __restrict__ pl,
    int* __restrict__ out) {
    __shared__ __align__(16) char SMEM[64 * PPITCH * 4];  // f32 P, then packed A
    __shared__ float    ls[4][64];
    __shared__ int      li[4][64];

    const int tid  = threadIdx.x;
    const int lane = tid & 63;
    const int w    = tid >> 6;
    const int quad = lane >> 4, col = lane & 15;
    const int qb   = blockIdx.x * 64;

    float* Pf = (float*)SMEM;

    // ======================= Phase 1: projection (LDS-free) =================
    const float* xr[4];
#pragma unroll
    for (int mt = 0; mt < 4; ++mt)
        xr[mt] = x + (size_t)(qb + mt * 16 + col) * D_IN + quad * 8;

    f32x4 acc[4][2];
#pragma unroll
    for (int mt = 0; mt < 4; ++mt)
#pragma unroll
        for (int h = 0; h < 2; ++h) acc[mt][h] = (f32x4){0.f, 0.f, 0.f, 0.f};

    // A raw prefetch (kb=0)
    float4 pA[4][2];
#pragma unroll
    for (int mt = 0; mt < 4; ++mt) {
        pA[mt][0] = *(const float4*)(xr[mt] + 0);
        pA[mt][1] = *(const float4*)(xr[mt] + 4);
    }
    // B prefetch (kb=0)
    f16x8 bhc[2], blc[2];
#pragma unroll
    for (int h = 0; h < 2; ++h) {
        const size_t off = ((size_t)(w * 2 + h) * 64 + lane) * 8;
        bhc[h] = *(const f16x8*)&rph[off];
        blc[h] = *(const f16x8*)&rpl[off];
    }

    for (int kb = 0; kb < 32; ++kb) {
        // split current A into hi/lo frags
        f16x8 ah1[4], al1[4];
#pragma unroll
        for (int mt = 0; mt < 4; ++mt) {
            const float vv[8] = {pA[mt][0].x, pA[mt][0].y, pA[mt][0].z, pA[mt][0].w,
                                 pA[mt][1].x, pA[mt][1].y, pA[mt][1].z, pA[mt][1].w};
            f16x8 hh, ll;
#pragma unroll
            for (int j = 0; j < 8; ++j) {
                const float v = vv[j] * 512.0f;
                const _Float16 hv = (_Float16)v;
                hh[j] = hv;
                ll[j] = (_Float16)(v - (float)hv);
            }
            ah1[mt] = hh;
            al1[mt] = ll;
        }

        // prefetch next-kb A
        if (kb + 1 < 32) {
#pragma unroll
            for (int mt = 0; mt < 4; ++mt) {
                pA[mt][0] = *(const float4*)(xr[mt] + (kb + 1) * 32);
                pA[mt][1] = *(const float4*)(xr[mt] + (kb + 1) * 32 + 4);
            }
        }

        // current B, prefetch next-kb B
        f16x8 bh1[2] = {bhc[0], bhc[1]};
        f16x8 bl1[2] = {blc[0], blc[1]};
        if (kb + 1 < 32) {
#pragma unroll
            for (int h = 0; h < 2; ++h) {
                const size_t off = ((size_t)((kb + 1) * 8 + w * 2 + h) * 64 + lane) * 8;
                bhc[h] = *(const f16x8*)&rph[off];
                blc[h] = *(const f16x8*)&rpl[off];
            }
        }

#pragma unroll
        for (int mt = 0; mt < 4; ++mt)
#pragma unroll
            for (int h = 0; h < 2; ++h)
                acc[mt][h] = __builtin_amdgcn_mfma_f32_16x16x32_f16(ah1[mt], bh1[h], acc[mt][h], 0, 0, 0);
#pragma unroll
        for (int mt = 0; mt < 4; ++mt)
#pragma unroll
            for (int h = 0; h < 2; ++h)
                acc[mt][h] = __builtin_amdgcn_mfma_f32_16x16x32_f16(ah1[mt], bl1[h], acc[mt][h], 0, 0, 0);
#pragma unroll
        for (int mt = 0; mt < 4; ++mt)
#pragma unroll
            for (int h = 0; h < 2; ++h)
                acc[mt][h] = __builtin_amdgcn_mfma_f32_16x16x32_f16(al1[mt], bh1[h], acc[mt][h], 0, 0, 0);
    }

    // Write proj*16 (f32) to LDS transpose buffer [query][k].
    // C/D: row(query) = mt*16 + quad*4 + r, col(k) = w*32 + h*16 + (lane&15).
#pragma unroll
    for (int mt = 0; mt < 4; ++mt)
#pragma unroll
        for (int h = 0; h < 2; ++h)
#pragma unroll
            for (int r = 0; r < 4; ++r) {
                const int row = mt * 16 + quad * 4 + r;
                const int cc  = w * 32 + h * 16 + col;
                Pf[row * PPITCH + cc] = acc[mt][h][r] * (1.0f / 2048.0f);
            }
    __syncthreads();

    // ============ A-frag extraction + LDS pack (ONCE; wave w -> mt=w) =======
    // A[m=col][k=quad*8+j], split hi/lo; same values as r11's extraction.
    f16x8 rh[4], rl[4];
#pragma unroll
    for (int kb = 0; kb < 4; ++kb) {
        const int base = (w * 16 + col) * PPITCH + kb * 32 + quad * 8;
        const float4 v0 = *(const float4*)&Pf[base];
        const float4 v1 = *(const float4*)&Pf[base + 4];
        const float vv[8] = {v0.x, v0.y, v0.z, v0.w, v1.x, v1.y, v1.z, v1.w};
        f16x8 hh, ll;
#pragma unroll
        for (int j = 0; j < 8; ++j) {
            const _Float16 hv = (_Float16)vv[j];
            hh[j] = hv;
            ll[j] = (_Float16)(vv[j] - (float)hv);
        }
        rh[kb] = hh;
        rl[kb] = ll;
    }
    __syncthreads();   // all Pf reads done; packed region may overwrite it

    _Float16* Aph = (_Float16*)SMEM;              // 16 KB: [mt*4+kb][lane][8]
    _Float16* Apl = (_Float16*)(SMEM + 16384);    // 16 KB
#pragma unroll
    for (int kb = 0; kb < 4; ++kb) {
        *(f16x8*)&Aph[((w * 4 + kb) * 64 + lane) * 8] = rh[kb];
        *(f16x8*)&Apl[((w * 4 + kb) * 64 + lane) * 8] = rl[kb];
    }
    __syncthreads();

    // ======================= Phase 2: scores + argmax =======================
    // A frags from packed LDS: bare ds_read_b128, zero VALU on remat.
    f16x8 ah[4][4], al[4][4];
#pragma unroll
    for (int mt = 0; mt < 4; ++mt)
#pragma unroll
        for (int kb = 0; kb < 4; ++kb) {
            ah[mt][kb] = *(const f16x8*)&Aph[((mt * 4 + kb) * 64 + lane) * 8];
            al[mt][kb] = *(const f16x8*)&Apl[((mt * 4 + kb) * 64 + lane) * 8];
        }

    float bs[16];
    int   bi[16];
#pragma unroll
    for (int s = 0; s < 16; ++s) { bs[s] = -FLT_MAX; bi[s] = 0; }

    // Wave w scans 16-code tiles [w*128, (w+1)*128) (codebook quarter).
    const int g0 = w * 128;

    // B single-buffered, software-pipelined (r11-validated):
    //   p1 ah x bh, p2 al x bh [reload bh], p3 ah x bl [reload bl]
    f16x8 bh[4], bl[4];
#pragma unroll
    for (int kb = 0; kb < 4; ++kb) {
        const size_t off = ((size_t)(g0 * 4 + kb) * 64 + lane) * 8;
        bh[kb] = *(const f16x8*)&ph[off];
        bl[kb] = *(const f16x8*)&pl[off];
    }

    for (int t = 0; t < 128; ++t) {
        f32x4 sacc[4];
#pragma unroll
        for (int mt = 0; mt < 4; ++mt) sacc[mt] = (f32x4){0.f, 0.f, 0.f, 0.f};

        // p1: ah x bh
        __builtin_amdgcn_s_setprio(1);
#pragma unroll
        for (int kb = 0; kb < 4; ++kb)
#pragma unroll
            for (int mt = 0; mt < 4; ++mt)
                sacc[mt] = __builtin_amdgcn_mfma_f32_16x16x32_f16(ah[mt][kb], bh[kb], sacc[mt], 0, 0, 0);
        // p2: al x bh  (bh dead after this pass)
#pragma unroll
        for (int kb = 0; kb < 4; ++kb)
#pragma unroll
            for (int mt = 0; mt < 4; ++mt)
                sacc[mt] = __builtin_amdgcn_mfma_f32_16x16x32_f16(al[mt][kb], bh[kb], sacc[mt], 0, 0, 0);
        __builtin_amdgcn_s_setprio(0);

        // reload bh <- tile t+1 (lands during p3)
        if (t + 1 < 128) {
            const int gn = g0 + t + 1;
#pragma unroll
            for (int kb = 0; kb < 4; ++kb) {
                const size_t off = ((size_t)(gn * 4 + kb) * 64 + lane) * 8;
                bh[kb] = *(const f16x8*)&ph[off];
            }
        }

        // p3: ah x bl  (bl dead after this pass)
        __builtin_amdgcn_s_setprio(1);
#pragma unroll
        for (int kb = 0; kb < 4; ++kb)
#pragma unroll
            for (int mt = 0; mt < 4; ++mt)
                sacc[mt] = __builtin_amdgcn_mfma_f32_16x16x32_f16(ah[mt][kb], bl[kb], sacc[mt], 0, 0, 0);
        __builtin_amdgcn_s_setprio(0);

        // reload bl <- tile t+1
        if (t + 1 < 128) {
            const int gn = g0 + t + 1;
#pragma unroll
            for (int kb = 0; kb < 4; ++kb) {
                const size_t off = ((size_t)(gn * 4 + kb) * 64 + lane) * 8;
                bl[kb] = *(const f16x8*)&pl[off];
            }
        }

        const int code = (g0 + t) * 16 + col;
#pragma unroll
        for (int mt = 0; mt < 4; ++mt)
#pragma unroll
            for (int r = 0; r < 4; ++r) {
                const float v = sacc[mt][r];
                const int s = mt * 4 + r;
                if (v > bs[s]) { bs[s] = v; bi[s] = code; }  // ascending codes: > keeps min idx
            }
    }

    // Reduce the 16 code-columns per query (lanes differ in low 4 bits).
#pragma unroll
    for (int s = 0; s < 16; ++s) {
#pragma unroll
        for (int m = 1; m < 16; m <<= 1) {
            const float os = __shfl_xor(bs[s], m);
            const int   oi = __shfl_xor(bi[s], m);
            if (os > bs[s] || (os == bs[s] && oi < bi[s])) { bs[s] = os; bi[s] = oi; }
        }
    }

    if (col == 0) {
#pragma unroll
        for (int mt = 0; mt < 4; ++mt)
#pragma unroll
            for (int r = 0; r < 4; ++r) {
                ls[w][mt * 16 + quad * 4 + r] = bs[mt * 4 + r];
                li[w][mt * 16 + quad * 4 + r] = bi[mt * 4 + r];
            }
    }
    __syncthreads();

    // Merge the 4 code quarters (wave 0 codes < wave 1 < ...: strict > keeps min idx).
    if (tid < 64) {
        const int q = tid;
        float s = ls[0][q];
        int   i = li[0][q];
#pragma unroll
        for (int ww = 1; ww < 4; ++ww) {
            const float os = ls[ww][q];
            if (os > s) { s = os; i = li[ww][q]; }
        }
        out[qb + q] = i;
    }
}

// ---------------------------------------------------------------------------
extern "C" void kernel_launch(void* const* d_in, const int* in_sizes, int n_in,
                              void* d_out, int out_size, void* d_ws, size_t ws_size,
                              hipStream_t stream) {
    const float* x  = (const float*)d_in[0];   // [8,4096,1024]
    const float* rp = (const float*)d_in[1];   // [1024,128]
    const float* cb = (const float*)d_in[2];   // [8192,128]
    int* out = (int*)d_out;                    // [8,4096] int32

    _Float16* ph  = (_Float16*)d_ws;                         // 2 MB
    _Float16* pl  = ph  + (size_t)CB_N * E_DIM;              // 2 MB
    _Float16* rph = pl  + (size_t)CB_N * E_DIM;              // 256 KB
    _Float16* rpl = rph + (size_t)D_IN * E_DIM;              // 256 KB

    pack_all_kernel<<<CB_N / 16 + 32, 256, 0, stream>>>(cb, ph, pl, rp, rph, rpl);
    fused_kernel<<<BN / 64, 256, 0, stream>>>(x, rph, rpl, ph, pl, out);
}